// Round 3
// baseline (237.729 us; speedup 1.0000x reference)
//
#include <hip/hip_runtime.h>

// DWT db4 depthwise stride-2 decomposition.
// x: [B=32, T=16384, C=64] f32 -> out: [B, T2=8190, 2C=128] f32
// out[b,t,c]    = sum_k lo[k] * x[b, reflect(2t+k-1), c]      (c < 64)
// out[b,t,64+c] = sum_k hi[k] * x[b, reflect(2t+k-1), c]
// reflect: m<0 -> -m ; m>T-1 -> 2(T-1)-m
//
// R3 structure (3rd submit: R1/R2 benches were container-acquisition infra
// failures; kernel never ran).  One thread = (4 channels via float4) x (QUAD
// of outputs t0..t0+3).  14-row window covers 4 outputs => 3.5 row-loads per
// output vs 5 in the pair version (-30% logical load traffic + VMEM insts).
// Interior fast path: when no reflection can occur (all quads except the
// first and last per batch), the 14 row addresses are base + i*256B -- the
// compiler folds them into one address register + 13-bit immediate offsets
// (max 3328 < 4096), killing the per-load reflect-clamp + 64-bit address
// chains.  All loads remain independent and issued before any use
// (~14 outstanding/thread).

#define BT    32
#define TT    16384
#define CC    64
#define T2    8190        // T/2 - 2
#define OC    128         // 2*CC
#define NQUAD 2048        // ceil(T2/4); last quad has only 2 valid outputs

__global__ __launch_bounds__(256) void dwt_db4_quad_kernel(
    const float* __restrict__ x,
    const float* __restrict__ dec_lo,
    const float* __restrict__ dec_hi,
    float* __restrict__ out)
{
    const int tid  = threadIdx.x;
    const int cg   = tid & 15;               // channel group: 4 ch via float4
    const int tq   = tid >> 4;               // 0..15: quad slot within block
    const int quad = blockIdx.x * 16 + tq;   // 0..2047 (grid.x = 128, exact)
    const int b    = blockIdx.y;

    const int t0 = quad * 4;
    const int c4 = cg * 4;
    const int m0 = 2 * t0 - 1;               // first input row of the window

    // Filters: uniform addresses -> scalar broadcast loads.
    float flo[8], fhi[8];
    #pragma unroll
    for (int k = 0; k < 8; ++k) { flo[k] = dec_lo[k]; fhi[k] = dec_hi[k]; }

    const float* __restrict__ xb = x + (size_t)b * TT * CC;

    // 14-row window: rows m0 .. m0+13 ; output t0+i (i=0..3) uses w[2i..2i+7].
    float4 w[14];
    if (m0 >= 0 && m0 + 13 <= TT - 1) {
        // Interior: affine addresses -> one base + immediate offsets.
        const float* __restrict__ p = xb + (size_t)m0 * CC + c4;
        #pragma unroll
        for (int i = 0; i < 14; ++i)
            w[i] = *reinterpret_cast<const float4*>(p + i * CC);
    } else {
        // Boundary (quad 0 / quad 2047 per batch): general reflect path.
        // Tail quad reads up to m=2*8191+6=16388 -> reflects to 16378 (safe);
        // the extra outputs are computed but not stored.
        #pragma unroll
        for (int i = 0; i < 14; ++i) {
            int m  = m0 + i;
            int mm = m < 0 ? -m : m;                          // left reflect
            mm     = mm > (TT - 1) ? 2 * (TT - 1) - mm : mm;  // right reflect
            w[i] = *reinterpret_cast<const float4*>(xb + (size_t)mm * CC + c4);
        }
    }

    float4 alo[4], ahi[4];
    #pragma unroll
    for (int i = 0; i < 4; ++i) {
        alo[i].x = alo[i].y = alo[i].z = alo[i].w = 0.0f;
        ahi[i].x = ahi[i].y = ahi[i].z = ahi[i].w = 0.0f;
    }

    // Fully unrolled: every w[]/alo[]/ahi[] index is compile-time constant
    // (runtime-indexed vector arrays would go to scratch).
    #pragma unroll
    for (int k = 0; k < 8; ++k) {
        #pragma unroll
        for (int i = 0; i < 4; ++i) {
            const float4 v = w[2 * i + k];
            alo[i].x = fmaf(flo[k], v.x, alo[i].x);
            alo[i].y = fmaf(flo[k], v.y, alo[i].y);
            alo[i].z = fmaf(flo[k], v.z, alo[i].z);
            alo[i].w = fmaf(flo[k], v.w, alo[i].w);
            ahi[i].x = fmaf(fhi[k], v.x, ahi[i].x);
            ahi[i].y = fmaf(fhi[k], v.y, ahi[i].y);
            ahi[i].z = fmaf(fhi[k], v.z, ahi[i].z);
            ahi[i].w = fmaf(fhi[k], v.w, ahi[i].w);
        }
    }

    // Stores: affine (one base + immediates, max 3*512+256 = 1792 < 4096).
    float* __restrict__ ob = out + (size_t)b * T2 * OC + (size_t)t0 * OC + c4;
    if (t0 + 4 <= T2) {
        #pragma unroll
        for (int i = 0; i < 4; ++i) {
            *reinterpret_cast<float4*>(ob + i * OC)      = alo[i];
            *reinterpret_cast<float4*>(ob + i * OC + CC) = ahi[i];
        }
    } else {
        // Tail quad (t0 = 8188): only t = 8188, 8189 are valid.
        #pragma unroll
        for (int i = 0; i < 4; ++i) {
            if (t0 + i < T2) {
                *reinterpret_cast<float4*>(ob + i * OC)      = alo[i];
                *reinterpret_cast<float4*>(ob + i * OC + CC) = ahi[i];
            }
        }
    }
}

extern "C" void kernel_launch(void* const* d_in, const int* in_sizes, int n_in,
                              void* d_out, int out_size, void* d_ws, size_t ws_size,
                              hipStream_t stream)
{
    const float* x      = (const float*)d_in[0];
    const float* dec_lo = (const float*)d_in[1];
    const float* dec_hi = (const float*)d_in[2];
    float*       out    = (float*)d_out;

    dim3 block(256);
    // 16 quads per block -> 2048/16 = 128 tiles; x 32 batches
    dim3 grid(NQUAD / 16, BT);

    hipLaunchKernelGGL(dwt_db4_quad_kernel, grid, block, 0, stream,
                       x, dec_lo, dec_hi, out);
}